// Round 11
// baseline (874.911 us; speedup 1.0000x reference)
//
#include <hip/hip_runtime.h>
#include <math.h>

#define B_ 16
#define C_ 64
#define T_ 99
#define KW_ 1250      // row length (K of the GEMM)
#define KP_ 1280      // K padded to chunk multiple
#define N_ 192        // 32 oc * 3 kh * 2 halves
#define M_ (B_*C_*100) // 102400
#define BM 32         // rows per block (full-K staging)
#define NCHUNK 40

typedef __attribute__((ext_vector_type(8))) _Float16 half8;
typedef __attribute__((ext_vector_type(2))) _Float16 half2_t;
typedef __attribute__((ext_vector_type(4))) float f32x4;
typedef __attribute__((ext_vector_type(2), aligned(8))) float f32x2;  // x rows are 8B-aligned (5000B stride)

// ---------------------------------------------------------------------------
// Kernel 0: one-shot weight conversion fp32 -> fp16, padded [192][1280].
// ---------------------------------------------------------------------------
__global__ __launch_bounds__(256) void wconv_kernel(const float* __restrict__ cw,
                                                    _Float16* __restrict__ wh)
{
    int n = blockIdx.x;               // 0..191
    int o = n / 6, rem = n - o * 6, kh = rem >> 1, hf = rem & 1;
    const float* src = cw + o * 7500 + kh * 2500 + hf * 1250;
    for (int k = threadIdx.x; k < KP_; k += 256)
        wh[n * KP_ + k] = (k < KW_) ? (_Float16)src[k] : (_Float16)0.f;
}

// ---------------------------------------------------------------------------
// Kernel 1 (R10): FUSED GEMM, BM=32 FULL-K one-shot staging.
// Evidence chain: A-read efficiency tracks contiguous-run length
//   (128B->1.04 TB/s R3; 512B->2.2 TB/s R5/R8 regardless of slab locality;
//   contiguous fills->6.4 TB/s).  R8's remap was NEUTRAL -> granule is the
//   lever, not slab placement.  Fix: consume whole 5KB rows in ONE visit.
// Block bt owns 32 consecutive xr rows = one 160KB contiguous slab, staged
// ONCE (wave w streams rows w*8..w*8+7 fully: 10 x 512B-coalesced f32x2
// issues/row, fp32->fp16 in flight), then 40 MFMA chunks from LDS with no
// further barriers.  Stage<->compute overlap across the 2 resident blocks.
//   - LDS 32x1280 fp16 = EXACTLY 80KB -> 2 blocks/CU.  No pad possible ->
//     bank conflicts killed by 16B-block XOR swizzle (blk ^= row&7) applied
//     on BOTH write and read sides: frag b128 reads = 8dw/bank (minimum),
//     stage writes 2-way (free).
//   - Waves split N: wave w covers n in [w*48, w*48+48); acc 2x3 f32x4.
//   - B fragments direct from L2 (480KB wh, ~1.5GB aggregate L2 traffic).
// Epilogue: R8's verified m' scatter (xr/100 -> (b*100+j)*64+c).
// Tail: cols 1250..1279 zeroed in LDS; wh zero-padded -> products match.
// ---------------------------------------------------------------------------
__global__ __launch_bounds__(256, 2) void gemm_kernel(const float* __restrict__ x,
                                                      const _Float16* __restrict__ wh,
                                                      _Float16* __restrict__ P)
{
    __shared__ __align__(16) _Float16 smA[BM * KP_];   // 80 KB, XOR-swizzled

    const int tid  = threadIdx.x;
    const int bt   = blockIdx.x;          // 0..3199
    const int lane = tid & 63;
    const int wave = tid >> 6;
    const int wn   = wave * 48;
    const int l15  = lane & 15;
    const int lq   = lane >> 4;
    const int l4   = lane >> 2;           // lane/4: 16B-block sub-index
    const int lm4  = lane & 3;            // 4B offset within 16B block

    // ---- stage: wave streams 8 whole rows (5KB each, contiguous) ----
    {
        const float* xb = x + (size_t)(bt * BM + wave * 8) * KW_;
#pragma unroll
        for (int rr = 0; rr < 8; rr++) {
            const int row = wave * 8 + rr;
            const float* xr = xb + (size_t)rr * KW_;
            _Float16* drow = smA + row * KP_;
            const int r7 = row & 7;
#pragma unroll
            for (int s = 0; s < 10; s++) {
                int c = s * 128 + lane * 2;          // even, 0..1278
                f32x2 v = (c <= KW_ - 2) ? *(const f32x2*)(xr + c)
                                         : (f32x2){0.f, 0.f};
                int blk = (s * 16 + l4) ^ r7;        // swizzled 16B-block idx
                *(half2_t*)(drow + blk * 8 + lm4 * 2) =
                    (half2_t){(_Float16)v.x, (_Float16)v.y};
            }
        }
    }
    __syncthreads();   // stage published; compute below is read-only on LDS

    // ---- compute: 40 chunks, no barriers ----
    const _Float16* bbase = wh + (size_t)(wn + l15) * KP_ + lq * 8;

    f32x4 acc[2][3];
#pragma unroll
    for (int mi = 0; mi < 2; mi++)
#pragma unroll
        for (int ni = 0; ni < 3; ni++) acc[mi][ni] = (f32x4){0.f, 0.f, 0.f, 0.f};

#pragma unroll 4
    for (int ck = 0; ck < NCHUNK; ck++) {
        half8 bfr[3];
#pragma unroll
        for (int ni = 0; ni < 3; ni++)
            bfr[ni] = *(const half8*)(bbase + (size_t)ni * 16 * KP_ + ck * 32);
        half8 afr[2];
#pragma unroll
        for (int mi = 0; mi < 2; mi++) {
            int row = mi * 16 + l15;
            int blk = (ck * 4 + lq) ^ (row & 7);     // read-side swizzle
            afr[mi] = *(const half8*)(smA + row * KP_ + blk * 8);
        }
#pragma unroll
        for (int mi = 0; mi < 2; mi++)
#pragma unroll
            for (int ni = 0; ni < 3; ni++)
                acc[mi][ni] = __builtin_amdgcn_mfma_f32_16x16x32_f16(
                    afr[mi], bfr[ni], acc[mi][ni], 0, 0, 0);
    }

    // epilogue: C/D layout col=lane&15, row=(lane>>4)*4+reg.
    // rloc -> xr = bt*32+rloc -> bc=xr/100, j=xr%100 ->
    // m' = (bc>>6)*6400 + j*64 + (bc&63); row's span in P is contiguous.
#pragma unroll
    for (int mi = 0; mi < 2; mi++) {
#pragma unroll
        for (int r2 = 0; r2 < 4; r2++) {
            int rloc = mi * 16 + lq * 4 + r2;
            int xr   = bt * BM + rloc;
            int bc   = xr / 100;
            int j    = xr - bc * 100;
            size_t mp = ((size_t)(bc >> 6) * 100 + j) * 64 + (bc & 63);
#pragma unroll
            for (int ni = 0; ni < 3; ni++) {
                int n = wn + ni * 16 + l15;
                P[mp * N_ + n] = (_Float16)acc[mi][ni][r2];
            }
        }
    }
}

// ---------------------------------------------------------------------------
// Kernel 2: combine halves + kh taps (replicate-pad clamp), relu, 1x1 conv,
// relu -> z[t][b*64+c]. One WG per (t,b); P blocks are contiguous fp16.
// LDS pad 193 (=1 mod 32): tap reads stride-193 across r=c -> 2-way = free.
// ---------------------------------------------------------------------------
__global__ __launch_bounds__(256) void combine_kernel(const _Float16* __restrict__ P,
                                                      const float* __restrict__ conv_b,
                                                      const float* __restrict__ c2w,
                                                      const float* __restrict__ c2b,
                                                      float* __restrict__ z)
{
    __shared__ float Pl[64][193];
    __shared__ float red[4][64];
    const int t   = blockIdx.x;     // 0..98
    const int b   = blockIdx.y;     // 0..15
    const int tid = threadIdx.x;
    const int c   = tid & 63;
    const int og  = tid >> 6;       // 0..3 -> o in [og*8, og*8+8)

    float v[8];
#pragma unroll
    for (int o = 0; o < 8; o++) v[o] = conv_b[og * 8 + o];

    for (int hf = 0; hf < 2; hf++) {
        const int j = t + hf;       // block index, <= 99
        const _Float16* Pb = P + (size_t)((b * 100 + j) * 64) * N_;  // 64x192 contiguous
        __syncthreads();            // protect Pl from previous phase's readers
#pragma unroll
        for (int i = 0; i < 6; i++) {
            int e   = i * 256 + tid;    // half8 unit index, 0..1535
            half8 hdat = *(const half8*)(Pb + e * 8);
            int row = e / 24;           // 24 half8 units per 192-wide row
            int col = (e - row * 24) * 8;
#pragma unroll
            for (int u = 0; u < 8; u++) Pl[row][col + u] = (float)hdat[u];
        }
        __syncthreads();
#pragma unroll
        for (int kh = 0; kh < 3; kh++) {
            int r = c + kh - 1;
            r = r < 0 ? 0 : (r > 63 ? 63 : r);   // replicate padding
#pragma unroll
            for (int o = 0; o < 8; o++)
                v[o] += Pl[r][(og * 8 + o) * 6 + kh * 2 + hf];
        }
    }

    float part = 0.f;
#pragma unroll
    for (int o = 0; o < 8; o++) part += fmaxf(v[o], 0.f) * c2w[og * 8 + o];
    red[og][c] = part;
    __syncthreads();
    if (og == 0) {
        float zz = red[0][c] + red[1][c] + red[2][c] + red[3][c] + c2b[0];
        z[t * (B_ * C_) + b * 64 + c] = fmaxf(zz, 0.f);   // [t][bc] coalesced
    }
}

// ---------------------------------------------------------------------------
// Kernel 3: scalar Elman RNN over T=99 + sigmoid. One thread per (b,c).
// z staged through LDS in 50-step tiles so the serial recurrence reads LDS.
// ---------------------------------------------------------------------------
__global__ __launch_bounds__(256) void rnn_kernel(const float* __restrict__ z,
                                                  const float* __restrict__ w_ih,
                                                  const float* __restrict__ w_hh,
                                                  const float* __restrict__ b_ih,
                                                  const float* __restrict__ b_hh,
                                                  const float* __restrict__ h0,
                                                  float* __restrict__ out)
{
    __shared__ float zs[50][256];
    const int tid = threadIdx.x;
    const int g   = blockIdx.x * 256 + tid;   // 0..1023 = b*64+c
    const int b   = g >> 6;
    const float wih  = w_ih[0];
    const float whh  = w_hh[0];
    const float bias = b_ih[0] + b_hh[0];
    float h = h0[b];
    for (int t0 = 0; t0 < T_; t0 += 50) {
        const int nt = (T_ - t0) < 50 ? (T_ - t0) : 50;
        __syncthreads();
        for (int tt = 0; tt < nt; tt++)
            zs[tt][tid] = z[(t0 + tt) * (B_ * C_) + g];   // coalesced rows
        __syncthreads();
        for (int tt = 0; tt < nt; tt++)
            h = tanhf(fmaf(wih, zs[tt][tid], fmaf(whh, h, bias)));
    }
    out[g] = 1.f / (1.f + expf(-h));
}

// ---------------------------------------------------------------------------
extern "C" void kernel_launch(void* const* d_in, const int* in_sizes, int n_in,
                              void* d_out, int out_size, void* d_ws, size_t ws_size,
                              hipStream_t stream)
{
    const float* x   = (const float*)d_in[0];
    const float* cw  = (const float*)d_in[1];
    const float* cb  = (const float*)d_in[2];
    const float* c2w = (const float*)d_in[3];
    const float* c2b = (const float*)d_in[4];
    const float* wih = (const float*)d_in[5];
    const float* whh = (const float*)d_in[6];
    const float* bih = (const float*)d_in[7];
    const float* bhh = (const float*)d_in[8];
    const float* h0  = (const float*)d_in[9];
    float* out = (float*)d_out;

    const size_t whbytes = (size_t)N_ * KP_ * sizeof(_Float16);   // 480 KB
    const size_t pbytes  = (size_t)M_ * N_ * sizeof(_Float16);    // 39.3 MB
    const size_t zbytes  = (size_t)B_ * C_ * T_ * sizeof(float);

    if (ws_size < whbytes + pbytes + zbytes) return;  // ws ~2GB; never hit

    _Float16* wh = (_Float16*)d_ws;
    _Float16* P  = (_Float16*)((char*)d_ws + whbytes);
    float*    z  = (float*)((char*)d_ws + whbytes + pbytes);

    wconv_kernel<<<N_, 256, 0, stream>>>(cw, wh);
    gemm_kernel<<<M_ / BM, 256, 0, stream>>>(x, wh, P);
    combine_kernel<<<dim3(T_, B_), 256, 0, stream>>>(P, cb, c2w, c2b, z);
    rnn_kernel<<<4, 256, 0, stream>>>(z, wih, whh, bih, bhh, h0, out);
}

// Round 12
// 834.665 us; speedup vs baseline: 1.0482x; 1.0482x over previous
//
#include <hip/hip_runtime.h>
#include <math.h>

#define B_ 16
#define C_ 64
#define T_ 99
#define KW_ 1250      // row length (K of the GEMM)
#define KP_ 1280      // K padded to chunk multiple
#define N_ 192        // 32 oc * 3 kh * 2 halves
#define M_ (B_*C_*100) // 102400
#define BM 64         // rows per block
#define NSC 10        // super-chunks of 128 k (512B fp32 per row)

typedef __attribute__((ext_vector_type(8))) _Float16 half8;
typedef __attribute__((ext_vector_type(4))) float f32x4;

#define GLD_LDS16(gp, lp) \
    __builtin_amdgcn_global_load_lds((const __attribute__((address_space(1))) void*)(gp), \
                                     (__attribute__((address_space(3))) void*)(lp), 16, 0, 0)

// ---------------------------------------------------------------------------
// Kernel 0: one-shot weight conversion fp32 -> fp16, padded [192][1280].
// ---------------------------------------------------------------------------
__global__ __launch_bounds__(256) void wconv_kernel(const float* __restrict__ cw,
                                                    _Float16* __restrict__ wh)
{
    int n = blockIdx.x;               // 0..191
    int o = n / 6, rem = n - o * 6, kh = rem >> 1, hf = rem & 1;
    const float* src = cw + o * 7500 + kh * 2500 + hf * 1250;
    for (int k = threadIdx.x; k < KP_; k += 256)
        wh[n * KP_ + k] = (k < KW_) ? (_Float16)src[k] : (_Float16)0.f;
}

// ---------------------------------------------------------------------------
// Kernel 1 (R12): FUSED GEMM, ASYNC global_load_lds A-staging (fp32 in LDS).
// Discriminating experiment: R5/R8 = 240us == 512MB / 2.2 TB/s effective on
// 512B-granule A reads with REG-ROUND-TRIP staging (load->wait->cvt->ds_write
// serialization each sc).  R10 (one-shot, no pipeline) = 338us, worse.
// R12 keeps R5's granule/mapping but stages A via global_load_lds:
//   - A lands in LDS as FP32 (no convert on store path); convert at frag
//     read (VALU 5% busy - free).  LDS 2 x [64][128] f32 = 64KB, dbuf.
//   - 8 gld_lds/wave/sc (1KB each: 2 rows x 512B); dist-2 issue (right after
//     read-release barrier) -> full sc-period to land; counted vmcnt(8)
//     before use-barrier, NEVER drained mid-loop (T3/T4).
//   - Swizzle per T21: LINEAR LDS dest (HW lane*16) + XOR-pre-swizzled
//     per-lane GLOBAL src block (g = lb ^ (row&7)) + XOR'd ds_read.  Frag
//     b128 reads: 2 lanes/bank (rows r,r+8) = free.
//   - B frags direct from L2 (1600 blocks x 480KB = 768MB L2 traffic).
// vmcnt audit (FIFO): at iter-sc wait, outstanding newest-first =
//   STAGE(sc+1)[8] | bfr(sc-1)[drained by MFMA-use waits] | STAGE(sc)[8];
//   vmcnt(8) -> everything older than newest 8 complete == STAGE(sc) landed;
//   STAGE(sc+1) untouched.  sc=9: vmcnt(0).  Per-wave vmcnt + barrier =
//   all waves' rows visible.
// Race audit: STAGE(sc+2)->buf issued AFTER barrier#2(sc) (all waves done
//   reading buf); compute(sc+1) uses buf^1; iter sc+2 vmcnt-waits it.
// K-tail (KW=1250): sc9/ckl3 frags cover k1248..1279; elements k>=1250
//   zeroed PRE-convert (garbage->NaN hazard); wh zero-padded -> exact.
//   x read may touch <=8B past the final row (page-slack safe).
// ---------------------------------------------------------------------------
__global__ __launch_bounds__(256, 2) void gemm_kernel(const float* __restrict__ x,
                                                      const _Float16* __restrict__ wh,
                                                      _Float16* __restrict__ P)
{
    __shared__ __align__(16) float smA[2][BM * 128];   // 2 x 32 KB fp32

    const int tid  = threadIdx.x;
    const int bt   = blockIdx.x;          // 0..1599
    const int lane = tid & 63;
    const int wave = tid >> 6;
    const int wm   = (wave & 1) * 32;
    const int wn   = (wave >> 1) * 96;
    const int l15  = lane & 15;
    const int lq   = lane >> 4;

    // staging lane geometry: wave w issue i covers rows 16w+2i, 16w+2i+1
    const int ls = lane >> 5;             // row parity within issue
    const int lb = lane & 31;             // LDS 16B-block index within row
    const float* xbase = x + (size_t)bt * BM * KW_;

    // STAGE(sc, buf): 8 async 1KB gld_lds; src block XOR-pre-swizzled.
#define STAGE(sc_, buf_) do {                                                    \
        _Pragma("unroll") for (int i_ = 0; i_ < 8; i_++) {                       \
            const int q_   = wave * 8 + i_;                                      \
            const int row_ = 2 * q_ + ls;                                        \
            const int g_   = lb ^ (row_ & 7);                                    \
            GLD_LDS16(xbase + (size_t)row_ * KW_ + (sc_) * 128 + g_ * 4,         \
                      &smA[buf_][q_ * 256]);                                     \
        }                                                                        \
    } while (0)

    // B fragment base: wh + (wn+ni*16+l15)*KP + ck*32 + lq*8 (16B aligned).
    const _Float16* bbase = wh + (size_t)(wn + l15) * KP_ + lq * 8;

    f32x4 acc[2][6];
#pragma unroll
    for (int mi = 0; mi < 2; mi++)
#pragma unroll
        for (int ni = 0; ni < 6; ni++) acc[mi][ni] = (f32x4){0.f, 0.f, 0.f, 0.f};

    STAGE(0, 0);
    STAGE(1, 1);

    for (int sc = 0; sc < NSC; sc++) {
        const int buf = sc & 1;
        const float* Ab = &smA[buf][0];
        const bool tail = (sc == NSC - 1);

        if (sc < NSC - 1) asm volatile("s_waitcnt vmcnt(8)" ::: "memory");
        else              asm volatile("s_waitcnt vmcnt(0)" ::: "memory");
        __builtin_amdgcn_s_barrier();        // STAGE(sc) visible to all waves
        __builtin_amdgcn_sched_barrier(0);

#pragma unroll
        for (int ckl = 0; ckl < 4; ckl++) {
            const int ck = sc * 4 + ckl;
            half8 bfr[6];
#pragma unroll
            for (int ni = 0; ni < 6; ni++)
                bfr[ni] = *(const half8*)(bbase + (size_t)ni * 16 * KP_ + ck * 32);

            half8 afr[2];
#pragma unroll
            for (int mi = 0; mi < 2; mi++) {
                const int row = wm + mi * 16 + l15;
                const int r7  = row & 7;
                const int b0  = ckl * 8 + lq * 2;
                f32x4 lo = *(const f32x4*)(Ab + row * 128 + ((b0    ) ^ r7) * 4);
                f32x4 hi = *(const f32x4*)(Ab + row * 128 + ((b0 + 1) ^ r7) * 4);
                if (tail && ckl == 3) {      // zero k>=1250 pre-convert
                    if (lq != 0) {
                        lo = (f32x4){0.f, 0.f, 0.f, 0.f};
                        hi = (f32x4){0.f, 0.f, 0.f, 0.f};
                    } else {
                        lo[2] = 0.f; lo[3] = 0.f;
                        hi = (f32x4){0.f, 0.f, 0.f, 0.f};
                    }
                }
                half8 a;
                a[0] = (_Float16)lo[0]; a[1] = (_Float16)lo[1];
                a[2] = (_Float16)lo[2]; a[3] = (_Float16)lo[3];
                a[4] = (_Float16)hi[0]; a[5] = (_Float16)hi[1];
                a[6] = (_Float16)hi[2]; a[7] = (_Float16)hi[3];
                afr[mi] = a;
            }
#pragma unroll
            for (int mi = 0; mi < 2; mi++)
#pragma unroll
                for (int ni = 0; ni < 6; ni++)
                    acc[mi][ni] = __builtin_amdgcn_mfma_f32_16x16x32_f16(
                        afr[mi], bfr[ni], acc[mi][ni], 0, 0, 0);
        }

        asm volatile("s_waitcnt lgkmcnt(0)" ::: "memory");
        __builtin_amdgcn_s_barrier();        // all waves done reading buf
        __builtin_amdgcn_sched_barrier(0);
        if (sc + 2 < NSC) STAGE(sc + 2, buf);  // async into freed buf
    }
#undef STAGE

    // epilogue: C/D layout col=lane&15, row=(lane>>4)*4+reg.
    // rloc -> xr = bt*64+rloc -> bc=xr/100, j=xr%100 ->
    // m' = (bc>>6)*6400 + j*64 + (bc&63); row's span in P contiguous.
#pragma unroll
    for (int mi = 0; mi < 2; mi++) {
#pragma unroll
        for (int r2 = 0; r2 < 4; r2++) {
            int rloc = wm + mi * 16 + lq * 4 + r2;
            int xr   = bt * BM + rloc;
            int bc   = xr / 100;
            int j    = xr - bc * 100;
            size_t mp = ((size_t)(bc >> 6) * 100 + j) * 64 + (bc & 63);
#pragma unroll
            for (int ni = 0; ni < 6; ni++) {
                int n = wn + ni * 16 + l15;
                P[mp * N_ + n] = (_Float16)acc[mi][ni][r2];
            }
        }
    }
}

// ---------------------------------------------------------------------------
// Kernel 2: combine halves + kh taps (replicate-pad clamp), relu, 1x1 conv,
// relu -> z[t][b*64+c]. One WG per (t,b); P blocks are contiguous fp16.
// LDS pad 193 (=1 mod 32): tap reads stride-193 across r=c -> 2-way = free.
// ---------------------------------------------------------------------------
__global__ __launch_bounds__(256) void combine_kernel(const _Float16* __restrict__ P,
                                                      const float* __restrict__ conv_b,
                                                      const float* __restrict__ c2w,
                                                      const float* __restrict__ c2b,
                                                      float* __restrict__ z)
{
    __shared__ float Pl[64][193];
    __shared__ float red[4][64];
    const int t   = blockIdx.x;     // 0..98
    const int b   = blockIdx.y;     // 0..15
    const int tid = threadIdx.x;
    const int c   = tid & 63;
    const int og  = tid >> 6;       // 0..3 -> o in [og*8, og*8+8)

    float v[8];
#pragma unroll
    for (int o = 0; o < 8; o++) v[o] = conv_b[og * 8 + o];

    for (int hf = 0; hf < 2; hf++) {
        const int j = t + hf;       // block index, <= 99
        const _Float16* Pb = P + (size_t)((b * 100 + j) * 64) * N_;  // 64x192 contiguous
        __syncthreads();            // protect Pl from previous phase's readers
#pragma unroll
        for (int i = 0; i < 6; i++) {
            int e   = i * 256 + tid;    // half8 unit index, 0..1535
            half8 hdat = *(const half8*)(Pb + e * 8);
            int row = e / 24;           // 24 half8 units per 192-wide row
            int col = (e - row * 24) * 8;
#pragma unroll
            for (int u = 0; u < 8; u++) Pl[row][col + u] = (float)hdat[u];
        }
        __syncthreads();
#pragma unroll
        for (int kh = 0; kh < 3; kh++) {
            int r = c + kh - 1;
            r = r < 0 ? 0 : (r > 63 ? 63 : r);   // replicate padding
#pragma unroll
            for (int o = 0; o < 8; o++)
                v[o] += Pl[r][(og * 8 + o) * 6 + kh * 2 + hf];
        }
    }

    float part = 0.f;
#pragma unroll
    for (int o = 0; o < 8; o++) part += fmaxf(v[o], 0.f) * c2w[og * 8 + o];
    red[og][c] = part;
    __syncthreads();
    if (og == 0) {
        float zz = red[0][c] + red[1][c] + red[2][c] + red[3][c] + c2b[0];
        z[t * (B_ * C_) + b * 64 + c] = fmaxf(zz, 0.f);   // [t][bc] coalesced
    }
}

// ---------------------------------------------------------------------------
// Kernel 3: scalar Elman RNN over T=99 + sigmoid. One thread per (b,c).
// z staged through LDS in 50-step tiles so the serial recurrence reads LDS.
// ---------------------------------------------------------------------------
__global__ __launch_bounds__(256) void rnn_kernel(const float* __restrict__ z,
                                                  const float* __restrict__ w_ih,
                                                  const float* __restrict__ w_hh,
                                                  const float* __restrict__ b_ih,
                                                  const float* __restrict__ b_hh,
                                                  const float* __restrict__ h0,
                                                  float* __restrict__ out)
{
    __shared__ float zs[50][256];
    const int tid = threadIdx.x;
    const int g   = blockIdx.x * 256 + tid;   // 0..1023 = b*64+c
    const int b   = g >> 6;
    const float wih  = w_ih[0];
    const float whh  = w_hh[0];
    const float bias = b_ih[0] + b_hh[0];
    float h = h0[b];
    for (int t0 = 0; t0 < T_; t0 += 50) {
        const int nt = (T_ - t0) < 50 ? (T_ - t0) : 50;
        __syncthreads();
        for (int tt = 0; tt < nt; tt++)
            zs[tt][tid] = z[(t0 + tt) * (B_ * C_) + g];   // coalesced rows
        __syncthreads();
        for (int tt = 0; tt < nt; tt++)
            h = tanhf(fmaf(wih, zs[tt][tid], fmaf(whh, h, bias)));
    }
    out[g] = 1.f / (1.f + expf(-h));
}

// ---------------------------------------------------------------------------
extern "C" void kernel_launch(void* const* d_in, const int* in_sizes, int n_in,
                              void* d_out, int out_size, void* d_ws, size_t ws_size,
                              hipStream_t stream)
{
    const float* x   = (const float*)d_in[0];
    const float* cw  = (const float*)d_in[1];
    const float* cb  = (const float*)d_in[2];
    const float* c2w = (const float*)d_in[3];
    const float* c2b = (const float*)d_in[4];
    const float* wih = (const float*)d_in[5];
    const float* whh = (const float*)d_in[6];
    const float* bih = (const float*)d_in[7];
    const float* bhh = (const float*)d_in[8];
    const float* h0  = (const float*)d_in[9];
    float* out = (float*)d_out;

    const size_t whbytes = (size_t)N_ * KP_ * sizeof(_Float16);   // 480 KB
    const size_t pbytes  = (size_t)M_ * N_ * sizeof(_Float16);    // 39.3 MB
    const size_t zbytes  = (size_t)B_ * C_ * T_ * sizeof(float);

    if (ws_size < whbytes + pbytes + zbytes) return;  // ws ~2GB; never hit

    _Float16* wh = (_Float16*)d_ws;
    _Float16* P  = (_Float16*)((char*)d_ws + whbytes);
    float*    z  = (float*)((char*)d_ws + whbytes + pbytes);

    wconv_kernel<<<N_, 256, 0, stream>>>(cw, wh);
    gemm_kernel<<<M_ / BM, 256, 0, stream>>>(x, wh, P);
    combine_kernel<<<dim3(T_, B_), 256, 0, stream>>>(P, cb, c2w, c2b, z);
    rnn_kernel<<<4, 256, 0, stream>>>(z, wih, whh, bih, bhh, h0, out);
}